// Round 11
// baseline (234.303 us; speedup 1.0000x reference)
//
#include <hip/hip_runtime.h>
#include <hip/hip_bf16.h>
#include <math.h>

#define B_TOTAL 16384
#define D 64
#define L_U 50
#define N_F 32
#define L_I 50
#define NROWS 100000   // N_USERS == N_ITEMS == 100000

// ---------------------------------------------------------------------------
// Setup: u[0..63]=W1@W3, u[64..]=W2@W3, u[128..]=W4@W6, u[192..]=W5@W6,
//        u[256..]=W7@W9, u[320..]=W8@W9
// ---------------------------------------------------------------------------
__global__ void graphrec_setup(const float* __restrict__ W1, const float* __restrict__ W2,
                               const float* __restrict__ W3, const float* __restrict__ W4,
                               const float* __restrict__ W5, const float* __restrict__ W6,
                               const float* __restrict__ W7, const float* __restrict__ W8,
                               const float* __restrict__ W9, float* __restrict__ u) {
    int t = threadIdx.x;           // 0..383
    int w = t >> 6;                // which of 6 vectors
    int d = t & 63;
    const float* Wm;
    const float* Wv;
    switch (w) {
        case 0: Wm = W1; Wv = W3; break;
        case 1: Wm = W2; Wv = W3; break;
        case 2: Wm = W4; Wv = W6; break;
        case 3: Wm = W5; Wv = W6; break;
        case 4: Wm = W7; Wv = W9; break;
        default: Wm = W8; Wv = W9; break;
    }
    float s = 0.f;
    #pragma unroll
    for (int j = 0; j < D; ++j) s = fmaf(Wm[d * D + j], Wv[j], s);
    u[w * D + d] = s;
}

// ---------------------------------------------------------------------------
// Wave-wide reductions via DPP (VALU only). row_shr 1/2/4/8, row_bcast15
// (rows 1,3), row_bcast31 (rows 2,3); readlane(63) -> wave-uniform result.
// ---------------------------------------------------------------------------
__device__ __forceinline__ float wred_sum(float x) {
    float t;
    #define STEP_ADD(ctrl, rmask)                                                        \
        t = __int_as_float(__builtin_amdgcn_update_dpp(0, __float_as_int(x),             \
                                                       ctrl, rmask, 0xf, false));        \
        x = x + t;
    STEP_ADD(0x111, 0xf)
    STEP_ADD(0x112, 0xf)
    STEP_ADD(0x114, 0xf)
    STEP_ADD(0x118, 0xf)
    STEP_ADD(0x142, 0xa)
    STEP_ADD(0x143, 0xc)
    #undef STEP_ADD
    return __int_as_float(__builtin_amdgcn_readlane(__float_as_int(x), 63));
}
__device__ __forceinline__ float wred_max(float x) {
    const int NEG_INF = 0xFF800000;
    float t;
    #define STEP_MAX(ctrl, rmask)                                                        \
        t = __int_as_float(__builtin_amdgcn_update_dpp(NEG_INF, __float_as_int(x),       \
                                                       ctrl, rmask, 0xf, false));        \
        x = fmaxf(x, t);
    STEP_MAX(0x111, 0xf)
    STEP_MAX(0x112, 0xf)
    STEP_MAX(0x114, 0xf)
    STEP_MAX(0x118, 0xf)
    STEP_MAX(0x142, 0xa)
    STEP_MAX(0x143, 0xc)
    #undef STEP_MAX
    return __int_as_float(__builtin_amdgcn_readlane(__float_as_int(x), 63));
}

// ---------------------------------------------------------------------------
// Projection precompute: for every table row, the two/three scalars the
// attention scores need. One wave handles item row b AND user row b.
//   iprojA[i] = { ei[i]·(W2@W3), ei[i]·W3 }          (attention A neighbors)
//   uprojB[v] =   eu[v]·(W5@W6)                       (attention B neighbors)
//   uprojC[v] = { eu[v]·(W8@W9), eu[v]·W9 }          (attention C neighbors)
// ---------------------------------------------------------------------------
__global__ __launch_bounds__(256) void graphrec_proj(
        const float* __restrict__ eu, const float* __restrict__ ei,
        const float* __restrict__ W3, const float* __restrict__ W9,
        const float* __restrict__ u,
        float2* __restrict__ iprojA, float* __restrict__ uprojB,
        float2* __restrict__ uprojC) {
    const int lane = threadIdx.x & 63;
    const int row = blockIdx.x * 4 + (threadIdx.x >> 6);
    const float e = ei[(size_t)row * D + lane];
    const float f = eu[(size_t)row * D + lane];
    float ia = wred_sum(e * u[64 + lane]);    // ei·(W2@W3)
    float iw = wred_sum(e * W3[lane]);        // ei·W3
    float ub = wred_sum(f * u[192 + lane]);   // eu·(W5@W6)
    float uc = wred_sum(f * u[320 + lane]);   // eu·(W8@W9)
    float uw = wred_sum(f * W9[lane]);        // eu·W9
    if (lane == 0) {
        iprojA[row] = make_float2(ia, iw);
        uprojB[row] = ub;
        uprojC[row] = make_float2(uc, uw);
    }
}

// ---------------------------------------------------------------------------
// Attention with precomputed projections: no LDS, no transpose.
//   sc_l = cq + proj1(idx_l) [+ r_l * proj2(idx_l)]   (8B gather per lane)
//   softmax across lanes via DPP (1 exp)
//   acc[dim=lane] = sum_l w_l * table[idx_l][lane]    (coalesced 256B rows)
// ---------------------------------------------------------------------------
template <int L, bool HAS_R>
__device__ __forceinline__ float attn_proj(float cq,
        const float* __restrict__ table,
        const float2* __restrict__ pj2, const float* __restrict__ pj1,
        int idxreg, float r, int lane) {
    float sc = -1e30f;
    if (lane < L) {
        if (HAS_R) {
            float2 p = pj2[(unsigned)idxreg];
            sc = fmaf(r, p.y, cq + p.x);
        } else {
            sc = cq + pj1[(unsigned)idxreg];
        }
    }
    float m = wred_max(sc);
    float e = __expf(sc - m);
    float s = wred_sum(e);
    float w = e * (1.0f / s);

    float acc = 0.f;
    #pragma unroll
    for (int l = 0; l < L; ++l) {
        float wl = __int_as_float(__builtin_amdgcn_readlane(__float_as_int(w), l));
        int ridx = __builtin_amdgcn_readlane(idxreg, l);
        acc = fmaf(wl, table[(size_t)(unsigned)ridx * D + lane], acc);
    }
    return acc;
}

__global__ __launch_bounds__(256) void graphrec_fwd(
        const int* __restrict__ user_ids, const int* __restrict__ item_ids,
        const int* __restrict__ uh_items, const float* __restrict__ uh_rat,
        const int* __restrict__ ufriends,
        const int* __restrict__ ih_users, const float* __restrict__ ih_rat,
        const float* __restrict__ eu, const float* __restrict__ ei,
        const float* __restrict__ fc1w, const float* __restrict__ fc1b,
        const float* __restrict__ fc2w, const float* __restrict__ fc2b,
        const float* __restrict__ u,
        const float2* __restrict__ iprojA, const float* __restrict__ uprojB,
        const float2* __restrict__ uprojC, float* __restrict__ out) {
    const int lane = threadIdx.x & 63;
    const int b = blockIdx.x * 4 + (threadIdx.x >> 6);

    // Per-lane neighbor metadata (lane l holds slot l).
    int idxA = 0, idxB = 0, idxC = 0;
    float rA = 0.f, rC = 0.f;
    if (lane < L_U) {
        idxA = uh_items[b * L_U + lane];
        rA   = uh_rat[b * L_U + lane];
        idxC = ih_users[b * L_I + lane];
        rC   = ih_rat[b * L_I + lane];
    }
    if (lane < N_F) idxB = ufriends[b * N_F + lane];

    const int uid = user_ids[b];
    const int iid = item_ids[b];
    const float qu = eu[(size_t)uid * D + lane];
    const float qi = ei[(size_t)iid * D + lane];

    // cq = q . (Wq@Wa) for each attention (DPP reduce -> uniform)
    const float cqa = wred_sum(qu * u[lane]);
    const float cqb = wred_sum(qu * u[128 + lane]);
    const float cqc = wred_sum(qi * u[256 + lane]);

    const float accA = attn_proj<L_U, true >(cqa, ei, iprojA, nullptr, idxA, rA, lane);
    const float accB = attn_proj<N_F, false>(cqb, eu, nullptr, uprojB, idxB, 0.f, lane);
    const float accC = attn_proj<L_I, true >(cqc, eu, uprojC, nullptr, idxC, rC, lane);

    const float uf  = qu + accA + accB;   // user_emb_final[lane]
    const float itf = qi + accC;          // item_emb_final[lane]

    // MLP: h_j = relu(fc1b[j] + sum_k c_k fc1w[k*64+j]); c_k via readlane,
    // fc1w reads coalesced 256 B, L1-hot.
    float h = fc1b[lane];
    #pragma unroll
    for (int k = 0; k < D; ++k) {
        float c = __int_as_float(__builtin_amdgcn_readlane(__float_as_int(uf), k));
        h = fmaf(c, fc1w[k * D + lane], h);
    }
    #pragma unroll
    for (int k = 0; k < D; ++k) {
        float c = __int_as_float(__builtin_amdgcn_readlane(__float_as_int(itf), k));
        h = fmaf(c, fc1w[(D + k) * D + lane], h);
    }
    h = fmaxf(h, 0.f);
    float o = wred_sum(h * fc2w[lane]);
    if (lane == 0) out[b] = o + fc2b[0];
}

extern "C" void kernel_launch(void* const* d_in, const int* in_sizes, int n_in,
                              void* d_out, int out_size, void* d_ws, size_t ws_size,
                              hipStream_t stream) {
    const int*   user_ids = (const int*)d_in[0];
    const int*   item_ids = (const int*)d_in[1];
    const int*   uh_items = (const int*)d_in[2];
    const float* uh_rat   = (const float*)d_in[3];
    const int*   ufriends = (const int*)d_in[4];
    const int*   ih_users = (const int*)d_in[5];
    const float* ih_rat   = (const float*)d_in[6];
    const float* eu       = (const float*)d_in[7];
    const float* ei       = (const float*)d_in[8];
    const float* W1 = (const float*)d_in[9];
    const float* W2 = (const float*)d_in[10];
    const float* W3 = (const float*)d_in[11];
    const float* W4 = (const float*)d_in[12];
    const float* W5 = (const float*)d_in[13];
    const float* W6 = (const float*)d_in[14];
    const float* W7 = (const float*)d_in[15];
    const float* W8 = (const float*)d_in[16];
    const float* W9 = (const float*)d_in[17];
    const float* fc1w = (const float*)d_in[18];
    const float* fc1b = (const float*)d_in[19];
    const float* fc2w = (const float*)d_in[20];
    const float* fc2b = (const float*)d_in[21];
    float* out = (float*)d_out;

    // Workspace layout (2,001,536 B total):
    //   [0, 1536)                u: six 64-float coefficient vectors
    //   [1536, 801536)           iprojA: float2[100000]
    //   [801536, 1201536)        uprojB: float [100000]
    //   [1201536, 2001536)       uprojC: float2[100000]
    float*  u      = (float*)d_ws;
    float2* iprojA = (float2*)((char*)d_ws + 1536);
    float*  uprojB = (float*) ((char*)d_ws + 801536);
    float2* uprojC = (float2*)((char*)d_ws + 1201536);

    graphrec_setup<<<1, 384, 0, stream>>>(W1, W2, W3, W4, W5, W6, W7, W8, W9, u);
    graphrec_proj<<<NROWS / 4, 256, 0, stream>>>(eu, ei, W3, W9, u,
                                                 iprojA, uprojB, uprojC);
    graphrec_fwd<<<B_TOTAL / 4, 256, 0, stream>>>(
        user_ids, item_ids, uh_items, uh_rat, ufriends, ih_users, ih_rat,
        eu, ei, fc1w, fc1b, fc2w, fc2b, u, iprojA, uprojB, uprojC, out);
}

// Round 12
// 231.110 us; speedup vs baseline: 1.0138x; 1.0138x over previous
//
#include <hip/hip_runtime.h>
#include <hip/hip_bf16.h>
#include <math.h>

#define B_TOTAL 16384
#define D 64
#define L_U 50
#define N_F 32
#define L_I 50
#define NROWS 100000   // N_USERS == N_ITEMS == 100000

// ---------------------------------------------------------------------------
// Setup: u[0..63]=W1@W3, u[64..]=W2@W3, u[128..]=W4@W6, u[192..]=W5@W6,
//        u[256..]=W7@W9, u[320..]=W8@W9
// ---------------------------------------------------------------------------
__global__ void graphrec_setup(const float* __restrict__ W1, const float* __restrict__ W2,
                               const float* __restrict__ W3, const float* __restrict__ W4,
                               const float* __restrict__ W5, const float* __restrict__ W6,
                               const float* __restrict__ W7, const float* __restrict__ W8,
                               const float* __restrict__ W9, float* __restrict__ u) {
    int t = threadIdx.x;           // 0..383
    int w = t >> 6;                // which of 6 vectors
    int d = t & 63;
    const float* Wm;
    const float* Wv;
    switch (w) {
        case 0: Wm = W1; Wv = W3; break;
        case 1: Wm = W2; Wv = W3; break;
        case 2: Wm = W4; Wv = W6; break;
        case 3: Wm = W5; Wv = W6; break;
        case 4: Wm = W7; Wv = W9; break;
        default: Wm = W8; Wv = W9; break;
    }
    float s = 0.f;
    #pragma unroll
    for (int j = 0; j < D; ++j) s = fmaf(Wm[d * D + j], Wv[j], s);
    u[w * D + d] = s;
}

// ---------------------------------------------------------------------------
// Wave-wide reductions via DPP (VALU only). row_shr 1/2/4/8, row_bcast15
// (rows 1,3), row_bcast31 (rows 2,3); readlane(63) -> wave-uniform result.
// ---------------------------------------------------------------------------
__device__ __forceinline__ float wred_sum(float x) {
    float t;
    #define STEP_ADD(ctrl, rmask)                                                        \
        t = __int_as_float(__builtin_amdgcn_update_dpp(0, __float_as_int(x),             \
                                                       ctrl, rmask, 0xf, false));        \
        x = x + t;
    STEP_ADD(0x111, 0xf)
    STEP_ADD(0x112, 0xf)
    STEP_ADD(0x114, 0xf)
    STEP_ADD(0x118, 0xf)
    STEP_ADD(0x142, 0xa)
    STEP_ADD(0x143, 0xc)
    #undef STEP_ADD
    return __int_as_float(__builtin_amdgcn_readlane(__float_as_int(x), 63));
}
__device__ __forceinline__ float wred_max(float x) {
    const int NEG_INF = 0xFF800000;
    float t;
    #define STEP_MAX(ctrl, rmask)                                                        \
        t = __int_as_float(__builtin_amdgcn_update_dpp(NEG_INF, __float_as_int(x),       \
                                                       ctrl, rmask, 0xf, false));        \
        x = fmaxf(x, t);
    STEP_MAX(0x111, 0xf)
    STEP_MAX(0x112, 0xf)
    STEP_MAX(0x114, 0xf)
    STEP_MAX(0x118, 0xf)
    STEP_MAX(0x142, 0xa)
    STEP_MAX(0x143, 0xc)
    #undef STEP_MAX
    return __int_as_float(__builtin_amdgcn_readlane(__float_as_int(x), 63));
}

// ---------------------------------------------------------------------------
// Projection precompute: for every table row, the score scalars.
//   iprojA[i] = { ei[i]·(W2@W3), ei[i]·W3 }
//   uprojB[v] =   eu[v]·(W5@W6)
//   uprojC[v] = { eu[v]·(W8@W9), eu[v]·W9 }
// ---------------------------------------------------------------------------
__global__ __launch_bounds__(256) void graphrec_proj(
        const float* __restrict__ eu, const float* __restrict__ ei,
        const float* __restrict__ W3, const float* __restrict__ W9,
        const float* __restrict__ u,
        float2* __restrict__ iprojA, float* __restrict__ uprojB,
        float2* __restrict__ uprojC) {
    const int lane = threadIdx.x & 63;
    const int row = blockIdx.x * 4 + (threadIdx.x >> 6);
    const float e = ei[(size_t)row * D + lane];
    const float f = eu[(size_t)row * D + lane];
    float ia = wred_sum(e * u[64 + lane]);    // ei·(W2@W3)
    float iw = wred_sum(e * W3[lane]);        // ei·W3
    float ub = wred_sum(f * u[192 + lane]);   // eu·(W5@W6)
    float uc = wred_sum(f * u[320 + lane]);   // eu·(W8@W9)
    float uw = wred_sum(f * W9[lane]);        // eu·W9
    if (lane == 0) {
        iprojA[row] = make_float2(ia, iw);
        uprojB[row] = ub;
        uprojC[row] = make_float2(uc, uw);
    }
}

// ---------------------------------------------------------------------------
// Attention, all in "chunk layout": lane=(sub=lane>>4, chunk=lane&15).
// Score phase (lane=slot): sc_l = cq + proj(idx_l); DPP softmax, 1 exp.
// Weighted sum: lane loads float4 chunk of row 4g+sub (4 rows / instruction,
// 4x256B coalesced segments), acc4 += w_l*n; xor16/32 shuffle-reduce so every
// lane holds its chunk's total over all rows. Tail slots (A/C: 50,51) have
// w=0 (exp(-1e30)=0) and idx=0 (valid row) -> no clamp needed.
// Returns float4 = this lane's chunk of the attended embedding.
// ---------------------------------------------------------------------------
template <int L, bool HAS_R>
__device__ __forceinline__ float4 attn_proj4(float cq,
        const float* __restrict__ table,
        const float2* __restrict__ pj2, const float* __restrict__ pj1,
        int idxreg, float r, int lane) {
    float sc = -1e30f;
    if (lane < L) {
        if (HAS_R) {
            float2 p = pj2[(unsigned)idxreg];
            sc = fmaf(r, p.y, cq + p.x);
        } else {
            sc = cq + pj1[(unsigned)idxreg];
        }
    }
    float m = wred_max(sc);
    float e = __expf(sc - m);
    float s = wred_sum(e);
    float w = e * (1.0f / s);                 // lanes >= L: w == 0

    const int sub = lane >> 4;
    const int co  = (lane & 15) << 2;         // float offset of 16B chunk
    float ax = 0.f, ay = 0.f, az = 0.f, aw = 0.f;
    #pragma unroll
    for (int g = 0; g < (L + 3) / 4; ++g) {
        const int sl4 = (4 * g + sub) << 2;   // bpermute byte addr of slot
        float wl = __int_as_float(__builtin_amdgcn_ds_bpermute(sl4, __float_as_int(w)));
        int ridx = __builtin_amdgcn_ds_bpermute(sl4, idxreg);
        float4 n = *(const float4*)(table + (size_t)(unsigned)ridx * D + co);
        ax = fmaf(wl, n.x, ax);
        ay = fmaf(wl, n.y, ay);
        az = fmaf(wl, n.z, az);
        aw = fmaf(wl, n.w, aw);
    }
    // reduce over the 4 sub-groups: lanes {c, c+16, c+32, c+48} -> all hold total
    ax += __shfl_xor(ax, 16); ay += __shfl_xor(ay, 16);
    az += __shfl_xor(az, 16); aw += __shfl_xor(aw, 16);
    ax += __shfl_xor(ax, 32); ay += __shfl_xor(ay, 32);
    az += __shfl_xor(az, 32); aw += __shfl_xor(aw, 32);
    return make_float4(ax, ay, az, aw);
}

__global__ __launch_bounds__(256) void graphrec_fwd(
        const int* __restrict__ user_ids, const int* __restrict__ item_ids,
        const int* __restrict__ uh_items, const float* __restrict__ uh_rat,
        const int* __restrict__ ufriends,
        const int* __restrict__ ih_users, const float* __restrict__ ih_rat,
        const float* __restrict__ eu, const float* __restrict__ ei,
        const float* __restrict__ fc1w, const float* __restrict__ fc1b,
        const float* __restrict__ fc2w, const float* __restrict__ fc2b,
        const float* __restrict__ u,
        const float2* __restrict__ iprojA, const float* __restrict__ uprojB,
        const float2* __restrict__ uprojC, float* __restrict__ out) {
    const int lane = threadIdx.x & 63;
    const int b = blockIdx.x * 4 + (threadIdx.x >> 6);
    const int cho = (lane & 15) << 2;         // chunk float offset

    // Per-lane neighbor metadata (lane l holds slot l).
    int idxA = 0, idxB = 0, idxC = 0;
    float rA = 0.f, rC = 0.f;
    if (lane < L_U) {
        idxA = uh_items[b * L_U + lane];
        rA   = uh_rat[b * L_U + lane];
        idxC = ih_users[b * L_I + lane];
        rC   = ih_rat[b * L_I + lane];
    }
    if (lane < N_F) idxB = ufriends[b * N_F + lane];

    const int uid = user_ids[b];
    const int iid = item_ids[b];

    // Query rows in chunk layout (each chunk replicated over the 4 subs).
    const float4 qu4 = *(const float4*)(eu + (size_t)uid * D + cho);
    const float4 qi4 = *(const float4*)(ei + (size_t)iid * D + cho);

    // cq = q.(Wq@Wa): chunk dot, wred_sum counts each chunk 4x -> *0.25 (exact).
    const float4 u1a = *(const float4*)(u + cho);          // W1@W3
    const float4 u1b = *(const float4*)(u + 128 + cho);    // W4@W6
    const float4 u1c = *(const float4*)(u + 256 + cho);    // W7@W9
    const float da = qu4.x * u1a.x + qu4.y * u1a.y + qu4.z * u1a.z + qu4.w * u1a.w;
    const float db = qu4.x * u1b.x + qu4.y * u1b.y + qu4.z * u1b.z + qu4.w * u1b.w;
    const float dc = qi4.x * u1c.x + qi4.y * u1c.y + qi4.z * u1c.z + qi4.w * u1c.w;
    const float cqa = 0.25f * wred_sum(da);
    const float cqb = 0.25f * wred_sum(db);
    const float cqc = 0.25f * wred_sum(dc);

    const float4 accA = attn_proj4<L_U, true >(cqa, ei, iprojA, nullptr, idxA, rA, lane);
    const float4 accB = attn_proj4<N_F, false>(cqb, eu, nullptr, uprojB, idxB, 0.f, lane);
    const float4 accC = attn_proj4<L_I, true >(cqc, eu, uprojC, nullptr, idxC, rC, lane);

    // Final embeddings, still in chunk layout.
    const float ufx = qu4.x + accA.x + accB.x;
    const float ufy = qu4.y + accA.y + accB.y;
    const float ufz = qu4.z + accA.z + accB.z;
    const float ufw = qu4.w + accA.w + accB.w;
    const float itx = qi4.x + accC.x;
    const float ity = qi4.y + accC.y;
    const float itz = qi4.z + accC.z;
    const float itw = qi4.w + accC.w;

    // MLP directly from chunk layout: c_k = comp(k&3) of chunk k>>2, which any
    // lane with (lane&15)==k>>2 holds; readlane(k>>2) is uniform per unrolled k.
    float h = fc1b[lane];
    const float ufc[4] = {ufx, ufy, ufz, ufw};
    const float itc[4] = {itx, ity, itz, itw};
    #pragma unroll
    for (int k = 0; k < D; ++k) {
        float c = __int_as_float(
            __builtin_amdgcn_readlane(__float_as_int(ufc[k & 3]), k >> 2));
        h = fmaf(c, fc1w[k * D + lane], h);
    }
    #pragma unroll
    for (int k = 0; k < D; ++k) {
        float c = __int_as_float(
            __builtin_amdgcn_readlane(__float_as_int(itc[k & 3]), k >> 2));
        h = fmaf(c, fc1w[(D + k) * D + lane], h);
    }
    h = fmaxf(h, 0.f);
    float o = wred_sum(h * fc2w[lane]);
    if (lane == 0) out[b] = o + fc2b[0];
}

extern "C" void kernel_launch(void* const* d_in, const int* in_sizes, int n_in,
                              void* d_out, int out_size, void* d_ws, size_t ws_size,
                              hipStream_t stream) {
    const int*   user_ids = (const int*)d_in[0];
    const int*   item_ids = (const int*)d_in[1];
    const int*   uh_items = (const int*)d_in[2];
    const float* uh_rat   = (const float*)d_in[3];
    const int*   ufriends = (const int*)d_in[4];
    const int*   ih_users = (const int*)d_in[5];
    const float* ih_rat   = (const float*)d_in[6];
    const float* eu       = (const float*)d_in[7];
    const float* ei       = (const float*)d_in[8];
    const float* W1 = (const float*)d_in[9];
    const float* W2 = (const float*)d_in[10];
    const float* W3 = (const float*)d_in[11];
    const float* W4 = (const float*)d_in[12];
    const float* W5 = (const float*)d_in[13];
    const float* W6 = (const float*)d_in[14];
    const float* W7 = (const float*)d_in[15];
    const float* W8 = (const float*)d_in[16];
    const float* W9 = (const float*)d_in[17];
    const float* fc1w = (const float*)d_in[18];
    const float* fc1b = (const float*)d_in[19];
    const float* fc2w = (const float*)d_in[20];
    const float* fc2b = (const float*)d_in[21];
    float* out = (float*)d_out;

    // Workspace layout (2,001,536 B total):
    //   [0, 1536)                u: six 64-float coefficient vectors
    //   [1536, 801536)           iprojA: float2[100000]
    //   [801536, 1201536)        uprojB: float [100000]
    //   [1201536, 2001536)       uprojC: float2[100000]
    float*  u      = (float*)d_ws;
    float2* iprojA = (float2*)((char*)d_ws + 1536);
    float*  uprojB = (float*) ((char*)d_ws + 801536);
    float2* uprojC = (float2*)((char*)d_ws + 1201536);

    graphrec_setup<<<1, 384, 0, stream>>>(W1, W2, W3, W4, W5, W6, W7, W8, W9, u);
    graphrec_proj<<<NROWS / 4, 256, 0, stream>>>(eu, ei, W3, W9, u,
                                                 iprojA, uprojB, uprojC);
    graphrec_fwd<<<B_TOTAL / 4, 256, 0, stream>>>(
        user_ids, item_ids, uh_items, uh_rat, ufriends, ih_users, ih_rat,
        eu, ei, fc1w, fc1b, fc2w, fc2b, u, iprojA, uprojB, uprojC, out);
}